// Round 1
// baseline (4305.196 us; speedup 1.0000x reference)
//
#include <hip/hip_runtime.h>
#include <math.h>

// Problem constants
constexpr int NB = 128;    // batch
constexpr int NH = 512;    // hidden
constexpr int NE = 256;    // embed
constexpr int NV = 32000;  // vocab
constexpr int NT = 32;     // steps
constexpr int BN = 64;     // v-tile
constexpr int BK = 64;     // k-tile
constexpr int NVB = NV / BN;  // 500 v-blocks

// ws layout (floats)
// hid   : 0        .. 65536   (128*512)
// emb   : 65536    .. 98304   (128*256)
// pmax  : 98304    .. 162304  (128*500)
// pidx  : 162304   .. 226304  (int, 128*500)
// psum  : 226304   .. 290304  (128*500)
// lps   : 290304   .. 290432  (128)
// mask  : 290432   .. 290560  (128)
// samp  : 290560   .. 290688  (int, 128)

// ---------------------------------------------------------------------------
// Kernel A: logits GEMM  C[b][v] = hid[b][:] . Wlin[v][:] + blin[v]
// block = 256 threads, grid = 500 (v-blocks of 64). BM=128 (all batch rows).
// Epilogue: per-(b, v-block) partial max / argmax / sum-exp(local) -> ws.
// Logits never go to global memory.
// ---------------------------------------------------------------------------
__global__ __launch_bounds__(256, 2)
void logits_kernel(const float* __restrict__ hid,   // [NB][NH]
                   const float* __restrict__ Wlin,  // [NV][NH]
                   const float* __restrict__ blin,  // [NV]
                   float* __restrict__ pmax, int* __restrict__ pidx,
                   float* __restrict__ psum)
{
    __shared__ float As[128][68];  // pad 4; XOR-swizzled float4 columns
    __shared__ float Bs[64][68];

    const int tid = threadIdx.x;
    const int vb  = blockIdx.x;
    const int v0  = vb * BN;
    const int ng  = tid & 15;       // n-group 0..15 (4 v each)
    const int mg  = tid >> 4;       // m-group 0..15 (8 b each)
    const int nbase = ng * 4;
    const int mbase = mg * 8;

    float acc[8][4];
#pragma unroll
    for (int i = 0; i < 8; i++)
#pragma unroll
        for (int j = 0; j < 4; j++) acc[i][j] = 0.f;

    for (int k0 = 0; k0 < NH; k0 += BK) {
        // stage A tile: 128 rows x 64 floats = 2048 float4, 8 per thread
#pragma unroll
        for (int i = 0; i < 8; i++) {
            int f4  = tid + i * 256;
            int row = f4 >> 4;          // 0..127
            int c4  = f4 & 15;          // 0..15
            float4 s = *(const float4*)(hid + (size_t)row * NH + k0 + c4 * 4);
            int sw = c4 ^ ((row >> 3) & 3);
            *(float4*)(&As[row][sw * 4]) = s;
        }
        // stage B tile: 64 rows x 64 floats = 1024 float4, 4 per thread
#pragma unroll
        for (int i = 0; i < 4; i++) {
            int f4  = tid + i * 256;
            int row = f4 >> 4;          // 0..63
            int c4  = f4 & 15;
            float4 s = *(const float4*)(Wlin + (size_t)(v0 + row) * NH + k0 + c4 * 4);
            int sw = c4 ^ (row >> 2);
            *(float4*)(&Bs[row][sw * 4]) = s;
        }
        __syncthreads();

#pragma unroll
        for (int ik4 = 0; ik4 < 16; ik4++) {
            float4 av[8], bv[4];
#pragma unroll
            for (int i = 0; i < 8; i++) {
                int m = mbase + i;
                av[i] = *(const float4*)(&As[m][(ik4 ^ ((m >> 3) & 3)) * 4]);
            }
#pragma unroll
            for (int j = 0; j < 4; j++) {
                int n = nbase + j;
                bv[j] = *(const float4*)(&Bs[n][(ik4 ^ (n >> 2)) * 4]);
            }
#pragma unroll
            for (int i = 0; i < 8; i++)
#pragma unroll
                for (int j = 0; j < 4; j++) {
                    acc[i][j] += av[i].x * bv[j].x;
                    acc[i][j] += av[i].y * bv[j].y;
                    acc[i][j] += av[i].z * bv[j].z;
                    acc[i][j] += av[i].w * bv[j].w;
                }
        }
        __syncthreads();
    }

    // epilogue: add bias, per-b partial (max, argmax, sumexp) over this block's 64 v
    float bias[4];
#pragma unroll
    for (int j = 0; j < 4; j++) bias[j] = blin[v0 + nbase + j];

#pragma unroll
    for (int i = 0; i < 8; i++) {
        int b = mbase + i;
        float m_ = acc[i][0] + bias[0];
        int  idx_ = v0 + nbase + 0;
#pragma unroll
        for (int j = 1; j < 4; j++) {
            float val = acc[i][j] + bias[j];
            if (val > m_) { m_ = val; idx_ = v0 + nbase + j; }
        }
        // reduce across the 16 lanes sharing this m-group (lanes are 16-aligned)
#pragma unroll
        for (int off = 1; off < 16; off <<= 1) {
            float om = __shfl_xor(m_, off);
            int   oi = __shfl_xor(idx_, off);
            if (om > m_ || (om == m_ && oi < idx_)) { m_ = om; idx_ = oi; }
        }
        float s_ = 0.f;
#pragma unroll
        for (int j = 0; j < 4; j++) s_ += expf(acc[i][j] + bias[j] - m_);
#pragma unroll
        for (int off = 1; off < 16; off <<= 1) s_ += __shfl_xor(s_, off);
        if (ng == 0) {
            pmax[b * NVB + vb] = m_;
            pidx[b * NVB + vb] = idx_;
            psum[b * NVB + vb] = s_;
        }
    }
}

// ---------------------------------------------------------------------------
// Kernel B: per-batch-row finalize. grid = 128 (one block per b), 256 threads.
// Reduce 500 partials -> global (max, argmax); combine sum-exp; update
// log_p_sent/mask state; write one-hot; gather embedding column.
// ---------------------------------------------------------------------------
__global__ __launch_bounds__(256, 4)
void emit_kernel(int t,
                 const float* __restrict__ pmax, const int* __restrict__ pidx,
                 const float* __restrict__ psum,
                 const float* __restrict__ Wemb,  // [NE][NV]
                 const float* __restrict__ bemb,  // [NE]
                 float* __restrict__ lps, float* __restrict__ maskp,
                 int* __restrict__ samp, float* __restrict__ emb,
                 float* __restrict__ out)
{
    const int b = blockIdx.x, tid = threadIdx.x;
    __shared__ float smax[4]; __shared__ int sidx[4]; __shared__ float ssum[4];
    __shared__ float bgmax; __shared__ int bgidx;

    float m_ = -INFINITY; int idx_ = 0x7fffffff;
    for (int c = tid; c < NVB; c += 256) {
        float v = pmax[b * NVB + c]; int ix = pidx[b * NVB + c];
        if (v > m_ || (v == m_ && ix < idx_)) { m_ = v; idx_ = ix; }
    }
#pragma unroll
    for (int off = 1; off < 64; off <<= 1) {
        float om = __shfl_xor(m_, off);
        int   oi = __shfl_xor(idx_, off);
        if (om > m_ || (om == m_ && oi < idx_)) { m_ = om; idx_ = oi; }
    }
    const int w = tid >> 6;
    if ((tid & 63) == 0) { smax[w] = m_; sidx[w] = idx_; }
    __syncthreads();
    if (tid == 0) {
        float gm = smax[0]; int gi = sidx[0];
        for (int i = 1; i < 4; i++)
            if (smax[i] > gm || (smax[i] == gm && sidx[i] < gi)) { gm = smax[i]; gi = sidx[i]; }
        bgmax = gm; bgidx = gi;
    }
    __syncthreads();
    const float gm = bgmax; const int gi = bgidx;

    float s_ = 0.f;
    for (int c = tid; c < NVB; c += 256)
        s_ += psum[b * NVB + c] * expf(pmax[b * NVB + c] - gm);
#pragma unroll
    for (int off = 1; off < 64; off <<= 1) s_ += __shfl_xor(s_, off);
    if ((tid & 63) == 0) ssum[w] = s_;
    __syncthreads();

    if (tid == 0) {
        float tot = ssum[0] + ssum[1] + ssum[2] + ssum[3];
        float lp = -logf(tot);  // log_softmax at the argmax: gm - gm - log(sum)
        float lpv, mk;
        if (t == 0) {
            lpv = lp;
            mk  = (gi == 0) ? 0.f : 1.f;   // EOS = 0
        } else {
            lpv = lps[b]; mk = maskp[b];
            lpv += mk * lp;
            mk  *= (gi == 0) ? 0.f : 1.f;
        }
        lps[b] = lpv; maskp[b] = mk; samp[b] = gi;
        out[(size_t)t * NB * NV + (size_t)b * NV + gi] = 1.0f;
        if (t == NT - 1) out[(size_t)NT * NB * NV + b] = lpv;
    }
    __syncthreads();
    // embedding gather: emb[b][e] = Wemb[e][gi] + bemb[e]   (NE == blockDim)
    emb[b * NE + tid] = Wemb[(size_t)tid * NV + gi] + bemb[tid];
}

// ---------------------------------------------------------------------------
// Kernel C: Elman cell. grid = 128 (per b), 256 threads (2 h each).
// hid_out[b][h] = tanh(Wih[h].emb[b] + bih[h] + Whh[h].hid_in[b] + bhh[h])
// ---------------------------------------------------------------------------
__global__ __launch_bounds__(256, 4)
void rnn_kernel(const float* __restrict__ hid_in, const float* __restrict__ emb,
                const float* __restrict__ Wih, const float* __restrict__ bih,
                const float* __restrict__ Whh, const float* __restrict__ bhh,
                float* __restrict__ hid_out)
{
    const int b = blockIdx.x, tid = threadIdx.x;
    __shared__ float es[NE];
    __shared__ float hs[NH];
    es[tid]        = emb[b * NE + tid];
    hs[tid]        = hid_in[b * NH + tid];
    hs[tid + 256]  = hid_in[b * NH + tid + 256];
    __syncthreads();

#pragma unroll
    for (int hh = 0; hh < 2; hh++) {
        int h = tid + hh * 256;
        float acc = bih[h] + bhh[h];
        const float4* wi = (const float4*)(Wih + (size_t)h * NE);
#pragma unroll 4
        for (int e4 = 0; e4 < NE / 4; e4++) {
            float4 w = wi[e4];
            acc += w.x * es[e4 * 4] + w.y * es[e4 * 4 + 1] +
                   w.z * es[e4 * 4 + 2] + w.w * es[e4 * 4 + 3];
        }
        const float4* wh = (const float4*)(Whh + (size_t)h * NH);
#pragma unroll 4
        for (int k4 = 0; k4 < NH / 4; k4++) {
            float4 w = wh[k4];
            acc += w.x * hs[k4 * 4] + w.y * hs[k4 * 4 + 1] +
                   w.z * hs[k4 * 4 + 2] + w.w * hs[k4 * 4 + 3];
        }
        hid_out[(size_t)b * NH + h] = tanhf(acc);
    }
}

extern "C" void kernel_launch(void* const* d_in, const int* in_sizes, int n_in,
                              void* d_out, int out_size, void* d_ws, size_t ws_size,
                              hipStream_t stream) {
    const float* z    = (const float*)d_in[0];
    const float* Wemb = (const float*)d_in[1];
    const float* bemb = (const float*)d_in[2];
    const float* Wih  = (const float*)d_in[3];
    const float* bih  = (const float*)d_in[4];
    const float* Whh  = (const float*)d_in[5];
    const float* bhh  = (const float*)d_in[6];
    const float* Wlin = (const float*)d_in[7];
    const float* blin = (const float*)d_in[8];
    float* out = (float*)d_out;

    float* ws   = (float*)d_ws;
    float* hid  = ws;
    float* emb  = ws + 65536;
    float* pmax = ws + 98304;
    int*   pidx = (int*)(ws + 162304);
    float* psum = ws + 226304;
    float* lps  = ws + 290304;
    float* mask = ws + 290432;
    int*   samp = (int*)(ws + 290560);

    // zero the one-hot sentences output (harness poisons d_out with 0xAA)
    hipMemsetAsync(d_out, 0, (size_t)NT * NB * NV * sizeof(float), stream);

    for (int t = 0; t < NT; t++) {
        const float* h = (t == 0) ? z : hid;
        logits_kernel<<<NVB, 256, 0, stream>>>(h, Wlin, blin, pmax, pidx, psum);
        emit_kernel<<<NB, 256, 0, stream>>>(t, pmax, pidx, psum, Wemb, bemb,
                                            lps, mask, samp, emb, out);
        if (t < NT - 1)
            rnn_kernel<<<NB, 256, 0, stream>>>(h, emb, Wih, bih, Whh, bhh, hid);
    }
}

// Round 3
// 2992.043 us; speedup vs baseline: 1.4389x; 1.4389x over previous
//
#include <hip/hip_runtime.h>
#include <math.h>

// Problem constants
constexpr int NB = 128;    // batch
constexpr int NH = 512;    // hidden
constexpr int NE = 256;    // embed
constexpr int NV = 32000;  // vocab
constexpr int NT = 32;     // steps
constexpr int NVBW = 1000; // 250 v-blocks * 4 wave-columns (32 vocab each)

typedef _Float16 half8 __attribute__((ext_vector_type(8)));
typedef float    f32x4 __attribute__((ext_vector_type(4)));

// ---------------------------------------------------------------------------
// Prep: fp32 -> f16 (8 elems/thread)
// ---------------------------------------------------------------------------
__global__ void f32_to_f16_kernel(const float* __restrict__ src,
                                  _Float16* __restrict__ dst, int n8)
{
    int i = blockIdx.x * 256 + threadIdx.x;
    if (i >= n8) return;
    float4 a = ((const float4*)src)[i * 2];
    float4 b = ((const float4*)src)[i * 2 + 1];
    half8 h = { (_Float16)a.x, (_Float16)a.y, (_Float16)a.z, (_Float16)a.w,
                (_Float16)b.x, (_Float16)b.y, (_Float16)b.z, (_Float16)b.w };
    ((half8*)dst)[i] = h;
}

// ---------------------------------------------------------------------------
// Kernel A: logits via f16 MFMA.  C[128][32000] = Ah[128][512] * Wh^T + blin
// grid = 250 (128 vocab per block), block = 512 (8 waves, 2x4 wave grid,
// wave tile 64 rows x 32 cols of 16x16x32 frags).
// LDS: [dbuf][mat A/B][row 128][k 64] f16, 16B-slot XOR swizzle (slot ^ row&7),
// staged with global_load_lds from pre-swizzled global addresses.
// Epilogue: per (b, 32-col group) top-2 (val,idx) + sum-exp partials.
// ---------------------------------------------------------------------------
__global__ __launch_bounds__(512, 1)
void logits_kernel(const _Float16* __restrict__ Ah,   // [128][512]
                   const _Float16* __restrict__ Wh,   // [32000][512]
                   const float* __restrict__ blin,    // [32000]
                   float* __restrict__ pm1, int* __restrict__ pi1,
                   float* __restrict__ pm2, int* __restrict__ pi2,
                   float* __restrict__ ps)
{
    __shared__ _Float16 sm[2][2][128][64];   // 64 KiB

    const int tid  = threadIdx.x;
    const int w    = tid >> 6;
    const int lane = tid & 63;
    const int wm   = w >> 2;      // 0..1
    const int wn   = w & 3;       // 0..3
    const int vb   = blockIdx.x;
    const int v0   = vb * 128;

    // staging source pointers: 2048 16B-slots per fill; wave w owns 256 (4 calls)
    // slot -> mat = slot>>10, r = (slot>>3)&127, sp = slot&7, src slot s = sp^(r&7)
    const _Float16* gp[4];
    unsigned ldsoff[4];
#pragma unroll
    for (int c = 0; c < 4; c++) {
        int slot = w * 256 + c * 64 + lane;
        int mat  = slot >> 10;
        int r    = (slot >> 3) & 127;
        int sp   = slot & 7;
        int s    = sp ^ (r & 7);
        const _Float16* base = mat ? (Wh + (size_t)(v0 + r) * NH)
                                   : (Ah + (size_t)r * NH);
        gp[c] = base + s * 8;
        ldsoff[c] = (unsigned)(w * 256 + c * 64) * 16;  // wave-uniform
    }

#define STAGE(db, k0)                                                          \
    do {                                                                       \
        _Pragma("unroll")                                                      \
        for (int c = 0; c < 4; c++) {                                          \
            __builtin_amdgcn_global_load_lds(                                  \
                (const __attribute__((address_space(1))) unsigned*)(gp[c] + (k0)), \
                (__attribute__((address_space(3))) unsigned*)((char*)&sm[db][0][0][0] + ldsoff[c]), \
                16, 0, 0);                                                     \
        }                                                                      \
    } while (0)

    f32x4 acc[4][2];
#pragma unroll
    for (int mi = 0; mi < 4; mi++)
#pragma unroll
        for (int ni = 0; ni < 2; ni++) acc[mi][ni] = {0.f, 0.f, 0.f, 0.f};

    // prologue
    STAGE(0, 0);
    asm volatile("s_waitcnt vmcnt(0)" ::: "memory");
    __builtin_amdgcn_sched_barrier(0);
    __builtin_amdgcn_s_barrier();

    int db = 0;
    for (int t = 0; t < 8; t++) {
        if (t < 7) STAGE(db ^ 1, (t + 1) * 64);   // prefetch overlaps compute
#pragma unroll
        for (int kk = 0; kk < 2; kk++) {
            const int sbase = kk * 4 + (lane >> 4);
            half8 af[4], bf[2];
#pragma unroll
            for (int mi = 0; mi < 4; mi++) {
                int r = wm * 64 + mi * 16 + (lane & 15);
                af[mi] = *(const half8*)&sm[db][0][r][(sbase ^ (r & 7)) * 8];
            }
#pragma unroll
            for (int ni = 0; ni < 2; ni++) {
                int rb = wn * 32 + ni * 16 + (lane & 15);
                bf[ni] = *(const half8*)&sm[db][1][rb][(sbase ^ (rb & 7)) * 8];
            }
#pragma unroll
            for (int mi = 0; mi < 4; mi++)
#pragma unroll
                for (int ni = 0; ni < 2; ni++)
                    acc[mi][ni] = __builtin_amdgcn_mfma_f32_16x16x32_f16(
                        af[mi], bf[ni], acc[mi][ni], 0, 0, 0);
        }
        asm volatile("s_waitcnt vmcnt(0)" ::: "memory");
        __builtin_amdgcn_sched_barrier(0);
        __builtin_amdgcn_s_barrier();
        db ^= 1;
    }
#undef STAGE

    // epilogue: top-2 + sumexp per row within this wave's 32 columns
    const int colbase = v0 + wn * 32 + (lane & 15);
    const float bias0 = blin[colbase];
    const float bias1 = blin[colbase + 16];
    const int cidx = vb * 4 + wn;     // 0..999

#pragma unroll
    for (int mi = 0; mi < 4; mi++) {
#pragma unroll
        for (int reg = 0; reg < 4; reg++) {
            const int b = wm * 64 + mi * 16 + (lane >> 4) * 4 + reg;
            const float va = acc[mi][0][reg] + bias0;
            const float vc = acc[mi][1][reg] + bias1;
            float a1, a2; int j1, j2;
            if (va >= vc) { a1 = va; j1 = colbase;      a2 = vc; j2 = colbase + 16; }
            else          { a1 = vc; j1 = colbase + 16; a2 = va; j2 = colbase; }
#pragma unroll
            for (int off = 1; off < 16; off <<= 1) {
                float o1 = __shfl_xor(a1, off), o2 = __shfl_xor(a2, off);
                int   k1 = __shfl_xor(j1, off), k2 = __shfl_xor(j2, off);
                float n1, n2; int m1, m2;
                bool ob = (o1 > a1) || (o1 == a1 && k1 < j1);
                if (ob) {
                    n1 = o1; m1 = k1;
                    bool t2 = (a1 > o2) || (a1 == o2 && j1 < k2);
                    if (t2) { n2 = a1; m2 = j1; } else { n2 = o2; m2 = k2; }
                } else {
                    n1 = a1; m1 = j1;
                    bool t2 = (o1 > a2) || (o1 == a2 && k1 < j2);
                    if (t2) { n2 = o1; m2 = k1; } else { n2 = a2; m2 = j2; }
                }
                a1 = n1; j1 = m1; a2 = n2; j2 = m2;
            }
            float s = __expf(va - a1) + __expf(vc - a1);
#pragma unroll
            for (int off = 1; off < 16; off <<= 1) s += __shfl_xor(s, off);
            if ((lane & 15) == 0) {
                pm1[b * NVBW + cidx] = a1;  pi1[b * NVBW + cidx] = j1;
                pm2[b * NVBW + cidx] = a2;  pi2[b * NVBW + cidx] = j2;
                ps [b * NVBW + cidx] = s;
            }
        }
    }
}

// ---------------------------------------------------------------------------
// Kernel B: fused emit (max/candidates/exact-rescore/log_p/one-hot/embedding)
// + Elman RNN cell. grid = 128 (per batch row), 256 threads.
// ---------------------------------------------------------------------------
__global__ __launch_bounds__(256, 2)
void emit_rnn_kernel(int t,
                     const float* __restrict__ hid_in,  // [128][512] fp32
                     const float* __restrict__ Wlin, const float* __restrict__ blin,
                     const float* __restrict__ pm1, const int* __restrict__ pi1,
                     const float* __restrict__ pm2, const int* __restrict__ pi2,
                     const float* __restrict__ ps,
                     const float* __restrict__ Wemb, const float* __restrict__ bemb,
                     const float* __restrict__ Wih, const float* __restrict__ bih,
                     const float* __restrict__ Whh, const float* __restrict__ bhh,
                     float* __restrict__ hid_out, _Float16* __restrict__ hidh_out,
                     float* __restrict__ lps, float* __restrict__ maskp,
                     float* __restrict__ out)
{
    constexpr float DELTA = 0.01f;
    constexpr int   MAXC  = 32;

    const int b = blockIdx.x, tid = threadIdx.x;
    const int w = tid >> 6, lane = tid & 63;

    __shared__ float red[4];
    __shared__ int   cand[MAXC];
    __shared__ float cval[MAXC];
    __shared__ int   ncand;
    __shared__ int   besti;
    __shared__ float es[NE];
    __shared__ float hs[NH];

    hs[tid]       = hid_in[(size_t)b * NH + tid];
    hs[tid + 256] = hid_in[(size_t)b * NH + tid + 256];
    if (tid == 0) ncand = 0;

    // phase 1: global max of pm1
    float m = -1e30f;
    for (int c = tid; c < NVBW; c += 256) m = fmaxf(m, pm1[b * NVBW + c]);
#pragma unroll
    for (int off = 1; off < 64; off <<= 1) m = fmaxf(m, __shfl_xor(m, off));
    if (lane == 0) red[w] = m;
    __syncthreads();
    const float gm = fmaxf(fmaxf(red[0], red[1]), fmaxf(red[2], red[3]));
    __syncthreads();

    // phase 2: softmax denominator + candidate collection
    float s = 0.f;
    for (int c = tid; c < NVBW; c += 256) {
        float p1 = pm1[b * NVBW + c];
        s += ps[b * NVBW + c] * __expf(p1 - gm);
        if (p1 >= gm - DELTA) {
            int pos = atomicAdd(&ncand, 1);
            if (pos < MAXC) cand[pos] = pi1[b * NVBW + c];
        }
        float p2 = pm2[b * NVBW + c];
        if (p2 >= gm - DELTA) {
            int pos = atomicAdd(&ncand, 1);
            if (pos < MAXC) cand[pos] = pi2[b * NVBW + c];
        }
    }
#pragma unroll
    for (int off = 1; off < 64; off <<= 1) s += __shfl_xor(s, off);
    if (lane == 0) red[w] = s;
    __syncthreads();
    const float tot = red[0] + red[1] + red[2] + red[3];
    const int nc = min(ncand, MAXC);

    // phase 3: exact fp32 rescore of candidates (one wave per candidate)
    for (int ci = w; ci < nc; ci += 4) {
        int tok = cand[ci];
        float4 h0 = ((const float4*)hs)[lane * 2];
        float4 h1 = ((const float4*)hs)[lane * 2 + 1];
        const float4* wv = (const float4*)(Wlin + (size_t)tok * NH);
        float4 w0 = wv[lane * 2], w1 = wv[lane * 2 + 1];
        float d = h0.x * w0.x + h0.y * w0.y + h0.z * w0.z + h0.w * w0.w
                + h1.x * w1.x + h1.y * w1.y + h1.z * w1.z + h1.w * w1.w;
#pragma unroll
        for (int off = 1; off < 64; off <<= 1) d += __shfl_xor(d, off);
        if (lane == 0) cval[ci] = d + blin[tok];
    }
    __syncthreads();

    // phase 4: pick argmax among candidates, update state, write one-hot
    if (tid == 0) {
        float bv = cval[0]; int bi = cand[0];
        for (int ci = 1; ci < nc; ci++)
            if (cval[ci] > bv || (cval[ci] == bv && cand[ci] < bi)) { bv = cval[ci]; bi = cand[ci]; }
        float lp = (bv - gm) - logf(tot);
        float lpv, mk;
        if (t == 0) { lpv = lp; mk = (bi == 0) ? 0.f : 1.f; }
        else {
            lpv = lps[b]; mk = maskp[b];
            lpv += mk * lp;
            mk *= (bi == 0) ? 0.f : 1.f;
        }
        lps[b] = lpv; maskp[b] = mk;
        out[(size_t)t * NB * NV + (size_t)b * NV + bi] = 1.0f;
        if (t == NT - 1) out[(size_t)NT * NB * NV + b] = lpv;
        besti = bi;
    }
    __syncthreads();
    const int gi = besti;

    if (t == NT - 1) return;

    // phase 5: embedding gather
    es[tid] = Wemb[(size_t)tid * NV + gi] + bemb[tid];
    __syncthreads();

    // phase 6: Elman cell (fp32)
#pragma unroll
    for (int hh = 0; hh < 2; hh++) {
        int h = tid + hh * 256;
        float acc = bih[h] + bhh[h];
        const float4* wi = (const float4*)(Wih + (size_t)h * NE);
#pragma unroll 4
        for (int e4 = 0; e4 < NE / 4; e4++) {
            float4 ww = wi[e4];
            acc += ww.x * es[e4 * 4] + ww.y * es[e4 * 4 + 1]
                 + ww.z * es[e4 * 4 + 2] + ww.w * es[e4 * 4 + 3];
        }
        const float4* wh = (const float4*)(Whh + (size_t)h * NH);
#pragma unroll 4
        for (int k4 = 0; k4 < NH / 4; k4++) {
            float4 ww = wh[k4];
            acc += ww.x * hs[k4 * 4] + ww.y * hs[k4 * 4 + 1]
                 + ww.z * hs[k4 * 4 + 2] + ww.w * hs[k4 * 4 + 3];
        }
        float v = tanhf(acc);
        hid_out[(size_t)b * NH + h]  = v;
        hidh_out[(size_t)b * NH + h] = (_Float16)v;
    }
}

// ---------------------------------------------------------------------------
extern "C" void kernel_launch(void* const* d_in, const int* in_sizes, int n_in,
                              void* d_out, int out_size, void* d_ws, size_t ws_size,
                              hipStream_t stream) {
    const float* z    = (const float*)d_in[0];
    const float* Wemb = (const float*)d_in[1];
    const float* bemb = (const float*)d_in[2];
    const float* Wih  = (const float*)d_in[3];
    const float* bih  = (const float*)d_in[4];
    const float* Whh  = (const float*)d_in[5];
    const float* bhh  = (const float*)d_in[6];
    const float* Wlin = (const float*)d_in[7];
    const float* blin = (const float*)d_in[8];
    float* out = (float*)d_out;

    char* ws = (char*)d_ws;
    _Float16* Wh    = (_Float16*)(ws);                 // 32,768,000 B
    _Float16* hidh  = (_Float16*)(ws + 32768000);      // 131,072 B
    _Float16* zh    = (_Float16*)(ws + 32899072);      // 131,072 B
    float*    hid   = (float*)   (ws + 33030144);      // 262,144 B
    float*    pm1   = (float*)   (ws + 33292288);      // 512,000 B
    int*      pi1   = (int*)     (ws + 33804288);
    float*    pm2   = (float*)   (ws + 34316288);
    int*      pi2   = (int*)     (ws + 34828288);
    float*    ps    = (float*)   (ws + 35340288);
    float*    lps   = (float*)   (ws + 35852288);
    float*    maskp = (float*)   (ws + 35852800);

    hipMemsetAsync(d_out, 0, (size_t)NT * NB * NV * sizeof(float), stream);
    f32_to_f16_kernel<<<NV * NH / 8 / 256, 256, 0, stream>>>(Wlin, Wh, NV * NH / 8);
    f32_to_f16_kernel<<<NB * NH / 8 / 256, 256, 0, stream>>>(z, zh, NB * NH / 8);

    for (int t = 0; t < NT; t++) {
        const float*    hin = (t == 0) ? z  : hid;
        const _Float16* ah  = (t == 0) ? zh : hidh;
        logits_kernel<<<250, 512, 0, stream>>>(ah, Wh, blin, pm1, pi1, pm2, pi2, ps);
        emit_rnn_kernel<<<NB, 256, 0, stream>>>(t, hin, Wlin, blin,
                                                pm1, pi1, pm2, pi2, ps,
                                                Wemb, bemb, Wih, bih, Whh, bhh,
                                                hid, hidh, lps, maskp, out);
    }
}